// Round 8
// baseline (234.027 us; speedup 1.0000x reference)
//
#include <hip/hip_runtime.h>
#include <math.h>

// Problem constants: B=16, K=4, T=64, N=128, F=16, H=32, NH=8, GH=32
// Sequences: 12288 = 2048 anchor + 2048 pos + 8192 neg. Graphs: 96 = 16+16+64.

typedef __bf16 bf16x8 __attribute__((ext_vector_type(8)));
typedef float  f32x4  __attribute__((ext_vector_type(4)));
typedef unsigned int u32x4 __attribute__((ext_vector_type(4)));

__device__ __forceinline__ float fast_rcp(float x) { return __builtin_amdgcn_rcpf(x); }
__device__ __forceinline__ float sigm(float x)     { return fast_rcp(1.f + __expf(-x)); }
__device__ __forceinline__ float tanh_fast(float x){ return fmaf(2.f, fast_rcp(1.f + __expf(-2.f * x)), -1.f); }

#define KEEP4(x) asm volatile("" : "+v"(x))

// ---------------------------------------------------------------------------
// LSTM via MFMA, barrier-free single-wave recurrence, DUAL-STREAM:
// each wave owns TWO independent 16-seq groups sharing the pinned weight
// fragments. The two recurrence chains interleave -> stream B's MFMAs/ds ops
// fill stream A's activation-latency stalls (and vice versa). Per-step h
// transpose through wave-private LDS halves (per-wave DS FIFO, no barriers).
// 4 MFMAs/tile: ax*wih_hi + ahi*whh_hi + ahi*whh_lo + alo*whh_hi.
// ---------------------------------------------------------------------------
__global__ __launch_bounds__(256, 1) void lstm_mfma_kernel(
    const float* __restrict__ anchor, const float* __restrict__ pos,
    const float* __restrict__ neg, const float* __restrict__ Wih,
    const float* __restrict__ Whh, const float* __restrict__ bias,
    float* __restrict__ hn)
{
    __shared__ unsigned int Hbuf[4][1024];  // per wave: [2 streams][16 m][32 j]
    const int tid  = threadIdx.x;
    const int w    = tid >> 6;
    const int lane = tid & 63;
    const int l15  = lane & 15;
    const int g4   = lane >> 4;
    unsigned int* hbA = Hbuf[w];
    unsigned int* hbB = Hbuf[w] + 512;

    #pragma unroll
    for (int i = 0; i < 16; ++i) Hbuf[w][lane + i * 64] = 0u;

    // B-fragments (u32x4, asm-pinned) + scalar bias
    u32x4 whhH[8], whhL[8], wihH[8];
    float bq[8];
    #pragma unroll
    for (int f = 0; f < 8; ++f) {
        const int G = f >> 1, Hh = f & 1;
        const int c = G * 32 + Hh * 16 + l15;
        bq[f] = bias[c];
        union { u32x4 u; bf16x8 v; } th, tl, ti;
        const float* wr = Whh + c * 32 + g4 * 8;
        #pragma unroll
        for (int i = 0; i < 8; ++i) {
            float wv = wr[i];
            __bf16 hi = (__bf16)wv;
            th.v[i] = hi;
            tl.v[i] = (__bf16)(wv - (float)hi);
        }
        if (g4 < 2) {
            const float* wr2 = Wih + c * 16 + g4 * 8;
            #pragma unroll
            for (int i = 0; i < 8; ++i) ti.v[i] = (__bf16)wr2[i];
        } else {
            #pragma unroll
            for (int i = 0; i < 8; ++i) ti.v[i] = (__bf16)0.f;
        }
        whhH[f] = th.u; whhL[f] = tl.u; wihH[f] = ti.u;
    }
    #pragma unroll
    for (int f = 0; f < 8; ++f) { KEEP4(whhH[f]); KEEP4(whhL[f]); KEEP4(wihH[f]); }

    // x sources: stream A = blk*128 + w*32 + l15, stream B = +16
    const bool xact = (g4 < 2);
    const float* xpA; const float* xpB;
    {
        const int sA = blockIdx.x * 128 + w * 32 + l15;
        const int sB = sA + 16;
        const float* base; int sl;
        if (sA < 2048)      { base = anchor; sl = sA; }
        else if (sA < 4096) { base = pos;    sl = sA - 2048; }
        else                { base = neg;    sl = sA - 4096; }
        xpA = base + (sl >> 7) * 131072 + (sl & 127) * 16 + (xact ? g4 * 8 : 0);
        if (sB < 2048)      { base = anchor; sl = sB; }
        else if (sB < 4096) { base = pos;    sl = sB - 2048; }
        else                { base = neg;    sl = sB - 4096; }
        xpB = base + (sl >> 7) * 131072 + (sl & 127) * 16 + (xact ? g4 * 8 : 0);
    }

    const float4 z4 = make_float4(0.f, 0.f, 0.f, 0.f);
    float4 eA0 = z4, eA1 = z4, oA0 = z4, oA1 = z4;
    float4 eB0 = z4, eB1 = z4, oB0 = z4, oB1 = z4;
    if (xact) {
        eA0 = *(const float4*)(xpA);        eA1 = *(const float4*)(xpA + 4);
        oA0 = *(const float4*)(xpA + 2048); oA1 = *(const float4*)(xpA + 2052);
        eB0 = *(const float4*)(xpB);        eB1 = *(const float4*)(xpB + 4);
        oB0 = *(const float4*)(xpB + 2048); oB1 = *(const float4*)(xpB + 2052);
    }

    float cstA[8] = {0,0,0,0,0,0,0,0}, hvA[8] = {0,0,0,0,0,0,0,0};
    float cstB[8] = {0,0,0,0,0,0,0,0}, hvB[8] = {0,0,0,0,0,0,0,0};

    const int c0  = g4 * 2;
    const int swz = (l15 & 3) << 1;
    const int ro0 = l15 * 32 + ((c0 ^ swz) << 2);
    const int ro1 = l15 * 32 + (((c0 + 1) ^ swz) << 2);

    #define CVT_AX(DST, X0, X1)                                                        \
        bf16x8 DST;                                                                    \
        DST[0]=(__bf16)X0.x; DST[1]=(__bf16)X0.y; DST[2]=(__bf16)X0.z; DST[3]=(__bf16)X0.w; \
        DST[4]=(__bf16)X1.x; DST[5]=(__bf16)X1.y; DST[6]=(__bf16)X1.z; DST[7]=(__bf16)X1.w;

    #define READ_H(HB, AHI, ALO)                                                       \
        union { unsigned int u[4]; bf16x8 v; } AHI, ALO;                               \
        {                                                                              \
            uint4 v0 = *(const uint4*)(HB + ro0);                                      \
            uint4 v1 = *(const uint4*)(HB + ro1);                                      \
            AHI.u[0] = __builtin_amdgcn_perm(v0.y, v0.x, 0x05040100u);                 \
            AHI.u[1] = __builtin_amdgcn_perm(v0.w, v0.z, 0x05040100u);                 \
            AHI.u[2] = __builtin_amdgcn_perm(v1.y, v1.x, 0x05040100u);                 \
            AHI.u[3] = __builtin_amdgcn_perm(v1.w, v1.z, 0x05040100u);                 \
            ALO.u[0] = __builtin_amdgcn_perm(v0.y, v0.x, 0x07060302u);                 \
            ALO.u[1] = __builtin_amdgcn_perm(v0.w, v0.z, 0x07060302u);                 \
            ALO.u[2] = __builtin_amdgcn_perm(v1.y, v1.x, 0x07060302u);                 \
            ALO.u[3] = __builtin_amdgcn_perm(v1.w, v1.z, 0x07060302u);                 \
        }

    #define ACT_WRITE(Z, CST, HV, HB)                                                  \
        _Pragma("unroll")                                                              \
        for (int Hh = 0; Hh < 2; ++Hh) {                                               \
            _Pragma("unroll")                                                          \
            for (int r = 0; r < 4; ++r) {                                              \
                const int idx = Hh * 4 + r;                                            \
                float zi = Z[0 + Hh][r] + bq[0 + Hh];                                  \
                float zf = Z[2 + Hh][r] + bq[2 + Hh];                                  \
                float zg = Z[4 + Hh][r] + bq[4 + Hh];                                  \
                float zo = Z[6 + Hh][r] + bq[6 + Hh];                                  \
                float cn = fmaf(sigm(zf), CST[idx], sigm(zi) * tanh_fast(zg));         \
                CST[idx] = cn;                                                         \
                float h = sigm(zo) * tanh_fast(cn);                                    \
                HV[idx] = h;                                                           \
                __bf16 hh_ = (__bf16)h;                                                \
                __bf16 hl_ = (__bf16)(h - (float)hh_);                                 \
                unsigned int pk = (unsigned int)__builtin_bit_cast(unsigned short, hh_)\
                                | ((unsigned int)__builtin_bit_cast(unsigned short, hl_) << 16); \
                const int mm = g4 * 4 + r;                                             \
                const int jw = Hh * 16 + l15;                                          \
                HB[mm * 32 + (((jw >> 2) ^ ((mm & 3) << 1)) << 2) + (jw & 3)] = pk;    \
            }                                                                          \
        }

    #define DUAL_STEP(XA0, XA1, XB0, XB1)                                              \
    {                                                                                  \
        READ_H(hbA, ahiA, aloA)                                                        \
        READ_H(hbB, ahiB, aloB)                                                        \
        CVT_AX(axA, XA0, XA1)                                                          \
        CVT_AX(axB, XB0, XB1)                                                          \
        f32x4 zA[8], zB[8];                                                            \
        _Pragma("unroll")                                                              \
        for (int f = 0; f < 8; ++f) {                                                  \
            f32x4 a = __builtin_amdgcn_mfma_f32_16x16x32_bf16(                         \
                axA, __builtin_bit_cast(bf16x8, wihH[f]), (f32x4)(0.f), 0, 0, 0);      \
            a = __builtin_amdgcn_mfma_f32_16x16x32_bf16(                               \
                ahiA.v, __builtin_bit_cast(bf16x8, whhH[f]), a, 0, 0, 0);              \
            a = __builtin_amdgcn_mfma_f32_16x16x32_bf16(                               \
                ahiA.v, __builtin_bit_cast(bf16x8, whhL[f]), a, 0, 0, 0);              \
            a = __builtin_amdgcn_mfma_f32_16x16x32_bf16(                               \
                aloA.v, __builtin_bit_cast(bf16x8, whhH[f]), a, 0, 0, 0);              \
            zA[f] = a;                                                                 \
            f32x4 b = __builtin_amdgcn_mfma_f32_16x16x32_bf16(                         \
                axB, __builtin_bit_cast(bf16x8, wihH[f]), (f32x4)(0.f), 0, 0, 0);      \
            b = __builtin_amdgcn_mfma_f32_16x16x32_bf16(                               \
                ahiB.v, __builtin_bit_cast(bf16x8, whhH[f]), b, 0, 0, 0);              \
            b = __builtin_amdgcn_mfma_f32_16x16x32_bf16(                               \
                ahiB.v, __builtin_bit_cast(bf16x8, whhL[f]), b, 0, 0, 0);              \
            b = __builtin_amdgcn_mfma_f32_16x16x32_bf16(                               \
                aloB.v, __builtin_bit_cast(bf16x8, whhH[f]), b, 0, 0, 0);              \
            zB[f] = b;                                                                 \
        }                                                                              \
        ACT_WRITE(zA, cstA, hvA, hbA)                                                  \
        ACT_WRITE(zB, cstB, hvB, hbB)                                                  \
    }

    for (int t = 0; t < 64; t += 2) {
        float4 cA0 = eA0, cA1 = eA1, cB0 = eB0, cB1 = eB1;
        if (xact && t + 2 < 64) {
            const float* pA = xpA + (t + 2) * 2048;
            const float* pB = xpB + (t + 2) * 2048;
            eA0 = *(const float4*)(pA); eA1 = *(const float4*)(pA + 4);
            eB0 = *(const float4*)(pB); eB1 = *(const float4*)(pB + 4);
        }
        DUAL_STEP(cA0, cA1, cB0, cB1);

        float4 dA0 = oA0, dA1 = oA1, dB0 = oB0, dB1 = oB1;
        if (xact && t + 3 < 64) {
            const float* pA = xpA + (t + 3) * 2048;
            const float* pB = xpB + (t + 3) * 2048;
            oA0 = *(const float4*)(pA); oA1 = *(const float4*)(pA + 4);
            oB0 = *(const float4*)(pB); oB1 = *(const float4*)(pB + 4);
        }
        DUAL_STEP(dA0, dA1, dB0, dB1);
    }
    #undef DUAL_STEP
    #undef ACT_WRITE
    #undef READ_H
    #undef CVT_AX

    const int baseA = blockIdx.x * 128 + w * 32;
    #pragma unroll
    for (int Hh = 0; Hh < 2; ++Hh) {
        #pragma unroll
        for (int r = 0; r < 4; ++r) {
            hn[(baseA + g4 * 4 + r) * 32 + Hh * 16 + l15]      = hvA[Hh * 4 + r];
            hn[(baseA + 16 + g4 * 4 + r) * 32 + Hh * 16 + l15] = hvB[Hh * 4 + r];
        }
    }
}

// FS layout: two 64-row halves with a 4-float shim between them so the two
// concurrently-read rows (s and s+64) sit 4 banks apart -> conflict-free b128.
__device__ __forceinline__ int fsoff(int n) { return n * 36 + ((n >> 6) << 2); }

// ---------------------------------------------------------------------------
// GATv2 layer 1, single-pass fused softmax+PV, 256 threads, bank-staggered FS.
// ---------------------------------------------------------------------------
__global__ __launch_bounds__(256) void gat1_kernel(
    const float* __restrict__ hn, const float* __restrict__ W1s,
    const float* __restrict__ W1d, const float* __restrict__ a1,
    const float* __restrict__ b1, float* __restrict__ h1heads)
{
    const int g = blockIdx.x >> 3, hd = blockIdx.x & 7;
    __shared__ float FSf[128 * 36 + 4];
    __shared__ float FD[128][36];
    __shared__ float AVr[32];
    __shared__ float As06[128];
    __shared__ float Ad06[128];
    const int tid = threadIdx.x;

    if (tid < 32) AVr[tid] = a1[hd * 32 + tid];

    // Phase A: fs = h@Ws, fd = h@Wd. thread = (o, 16-row slab).
    {
        const int o = tid & 31, nb = tid >> 5;
        float wcs[32], wcd[32];
        const float* wsp = W1s + hd * 1024 + o;
        const float* wdp = W1d + hd * 1024 + o;
        #pragma unroll
        for (int k = 0; k < 32; ++k) { wcs[k] = wsp[k * 32]; wcd[k] = wdp[k * 32]; }
        const float* hp = hn + g * 4096 + nb * 512;
        #pragma unroll 1
        for (int n = 0; n < 16; ++n) {
            float a0 = 0.f, a1_ = 0.f, b0 = 0.f, b1_ = 0.f;
            #pragma unroll
            for (int k0 = 0; k0 < 32; k0 += 4) {
                float4 hv = *(const float4*)(hp + n * 32 + k0);
                a0 = fmaf(hv.x, wcs[k0+0], a0); b0 = fmaf(hv.x, wcd[k0+0], b0);
                a1_ = fmaf(hv.y, wcs[k0+1], a1_); b1_ = fmaf(hv.y, wcd[k0+1], b1_);
                a0 = fmaf(hv.z, wcs[k0+2], a0); b0 = fmaf(hv.z, wcd[k0+2], b0);
                a1_ = fmaf(hv.w, wcs[k0+3], a1_); b1_ = fmaf(hv.w, wcd[k0+3], b1_);
            }
            const int row = nb * 16 + n;
            FSf[fsoff(row) + o] = a0 + a1_;
            FD[row][o] = b0 + b1_;
        }
    }
    __syncthreads();

    if (tid < 128) {
        float ss = 0.f, sd = 0.f;
        const float* fr = FSf + fsoff(tid);
        #pragma unroll
        for (int oo = 0; oo < 32; ++oo) {
            int o = (oo + tid) & 31;
            float a = AVr[o];
            ss = fmaf(a, fr[o], ss);
            sd = fmaf(a, FD[tid][o], sd);
        }
        As06[tid] = 0.6f * ss;
        Ad06[tid] = 0.6f * sd;
    }
    __syncthreads();

    const int d = tid >> 1, sbase = (tid & 1) << 6;
    float fdr[32], avs[32];
    #pragma unroll
    for (int c = 0; c < 8; ++c) {
        float4 v = *(const float4*)&FD[d][c * 4];
        fdr[c*4+0] = v.x; fdr[c*4+1] = v.y; fdr[c*4+2] = v.z; fdr[c*4+3] = v.w;
        float4 w = *(const float4*)&AVr[c * 4];
        avs[c*4+0] = 0.4f * w.x; avs[c*4+1] = 0.4f * w.y;
        avs[c*4+2] = 0.4f * w.z; avs[c*4+3] = 0.4f * w.w;
    }
    const float adc = Ad06[d];

    float Z = 0.f;
    float acc[32];
    #pragma unroll
    for (int o = 0; o < 32; ++o) acc[o] = 0.f;
    #pragma unroll 1
    for (int si = 0; si < 64; ++si) {
        const int s = sbase + si;
        const float* fr = FSf + fsoff(s);
        float4 fa[8];
        #pragma unroll
        for (int c = 0; c < 8; ++c) fa[c] = *(const float4*)(fr + c * 4);
        float c0 = 0.f, c1 = 0.f, c2 = 0.f, c3 = 0.f;
        #pragma unroll
        for (int c = 0; c < 8; ++c) {
            float e0 = fdr[c*4+0] + fa[c].x; c0 = fmaf(avs[c*4+0], __builtin_fabsf(e0), c0);
            float e1 = fdr[c*4+1] + fa[c].y; c1 = fmaf(avs[c*4+1], __builtin_fabsf(e1), c1);
            float e2 = fdr[c*4+2] + fa[c].z; c2 = fmaf(avs[c*4+2], __builtin_fabsf(e2), c2);
            float e3 = fdr[c*4+3] + fa[c].w; c3 = fmaf(avs[c*4+3], __builtin_fabsf(e3), c3);
        }
        float v = adc + As06[s] + ((c0 + c1) + (c2 + c3));
        float e = (s == d) ? 0.f : __expf(v);
        Z += e;
        #pragma unroll
        for (int c = 0; c < 8; ++c) {
            acc[c*4+0] = fmaf(e, fa[c].x, acc[c*4+0]);
            acc[c*4+1] = fmaf(e, fa[c].y, acc[c*4+1]);
            acc[c*4+2] = fmaf(e, fa[c].z, acc[c*4+2]);
            acc[c*4+3] = fmaf(e, fa[c].w, acc[c*4+3]);
        }
    }
    Z += __shfl_xor(Z, 1);
    const float rz = fast_rcp(Z);
    #pragma unroll
    for (int o = 0; o < 32; ++o) acc[o] += __shfl_xor(acc[o], 1);

    float* dst = h1heads + ((size_t)((g * 8 + hd) * 128 + d)) * 32;
    const float* bp = b1 + hd * 32;
    if ((tid & 1) == 0) {
        #pragma unroll
        for (int c = 0; c < 4; ++c) {
            float4 v;
            v.x = fmaf(acc[c*4+0], rz, bp[c*4+0]);
            v.y = fmaf(acc[c*4+1], rz, bp[c*4+1]);
            v.z = fmaf(acc[c*4+2], rz, bp[c*4+2]);
            v.w = fmaf(acc[c*4+3], rz, bp[c*4+3]);
            *(float4*)(dst + c * 4) = v;
        }
    } else {
        #pragma unroll
        for (int c = 4; c < 8; ++c) {
            float4 v;
            v.x = fmaf(acc[c*4+0], rz, bp[c*4+0]);
            v.y = fmaf(acc[c*4+1], rz, bp[c*4+1]);
            v.z = fmaf(acc[c*4+2], rz, bp[c*4+2]);
            v.w = fmaf(acc[c*4+3], rz, bp[c*4+3]);
            *(float4*)(dst + c * 4) = v;
        }
    }
}

// ---------------------------------------------------------------------------
// GATv2 layer 2, single-pass, bank-staggered FS: one block per graph.
// ---------------------------------------------------------------------------
__global__ __launch_bounds__(256) void gat2_kernel(
    const float* __restrict__ h1heads, const float* __restrict__ W2s,
    const float* __restrict__ W2d, const float* __restrict__ a2,
    const float* __restrict__ b2, float* __restrict__ pooled)
{
    const int g = blockIdx.x;
    __shared__ float HS[128][36];
    __shared__ float FSf[128 * 36 + 4];
    __shared__ float FD[128][36];     // reused as OUT after the fused pass
    __shared__ float AVr[32];
    __shared__ float As06[128];
    __shared__ float Ad06[128];
    const int tid = threadIdx.x;

    if (tid < 32) AVr[tid] = a2[tid];

    {
        #pragma unroll
        for (int i = 0; i < 4; ++i) {
            int idx4 = i * 256 + tid;
            float sx = 0.f, sy = 0.f, sz = 0.f, sw = 0.f;
            #pragma unroll
            for (int hdd = 0; hdd < 8; ++hdd) {
                const float4* src = (const float4*)(h1heads + (size_t)(g * 8 + hdd) * 4096);
                float4 v = src[idx4];
                sx += v.x; sy += v.y; sz += v.z; sw += v.w;
            }
            int n = idx4 >> 3, k0 = (idx4 & 7) * 4;
            float4 r; r.x = sx * 0.125f; r.y = sy * 0.125f; r.z = sz * 0.125f; r.w = sw * 0.125f;
            *(float4*)&HS[n][k0] = r;
        }
    }
    __syncthreads();

    {
        const int o = tid & 31, nb = tid >> 5;
        float wcs[32], wcd[32];
        const float* wsp = W2s + o;
        const float* wdp = W2d + o;
        #pragma unroll
        for (int k = 0; k < 32; ++k) { wcs[k] = wsp[k * 32]; wcd[k] = wdp[k * 32]; }
        #pragma unroll 1
        for (int n = nb * 16; n < nb * 16 + 16; ++n) {
            float a0 = 0.f, a1_ = 0.f, b0 = 0.f, b1_ = 0.f;
            #pragma unroll
            for (int k0 = 0; k0 < 32; k0 += 4) {
                const float4 hv = *(const float4*)&HS[n][k0];
                a0 = fmaf(hv.x, wcs[k0+0], a0); b0 = fmaf(hv.x, wcd[k0+0], b0);
                a1_ = fmaf(hv.y, wcs[k0+1], a1_); b1_ = fmaf(hv.y, wcd[k0+1], b1_);
                a0 = fmaf(hv.z, wcs[k0+2], a0); b0 = fmaf(hv.z, wcd[k0+2], b0);
                a1_ = fmaf(hv.w, wcs[k0+3], a1_); b1_ = fmaf(hv.w, wcd[k0+3], b1_);
            }
            FSf[fsoff(n) + o] = a0 + a1_;
            FD[n][o] = b0 + b1_;
        }
    }
    __syncthreads();

    if (tid < 128) {
        float ss = 0.f, sd = 0.f;
        const float* fr = FSf + fsoff(tid);
        #pragma unroll
        for (int oo = 0; oo < 32; ++oo) {
            int o = (oo + tid) & 31;
            float a = AVr[o];
            ss = fmaf(a, fr[o], ss);
            sd = fmaf(a, FD[tid][o], sd);
        }
        As06[tid] = 0.6f * ss;
        Ad06[tid] = 0.6f * sd;
    }
    __syncthreads();

    const int d = tid >> 1, sbase = (tid & 1) << 6;
    float fdr[32], avs[32];
    #pragma unroll
    for (int c = 0; c < 8; ++c) {
        float4 v = *(const float4*)&FD[d][c * 4];
        fdr[c*4+0] = v.x; fdr[c*4+1] = v.y; fdr[c*4+2] = v.z; fdr[c*4+3] = v.w;
        float4 w = *(const float4*)&AVr[c * 4];
        avs[c*4+0] = 0.4f * w.x; avs[c*4+1] = 0.4f * w.y;
        avs[c*4+2] = 0.4f * w.z; avs[c*4+3] = 0.4f * w.w;
    }
    const float adc = Ad06[d];

    float Z = 0.f;
    float acc[32];
    #pragma unroll
    for (int o = 0; o < 32; ++o) acc[o] = 0.f;
    #pragma unroll 1
    for (int si = 0; si < 64; ++si) {
        const int s = sbase + si;
        const float* fr = FSf + fsoff(s);
        float4 fa[8];
        #pragma unroll
        for (int c = 0; c < 8; ++c) fa[c] = *(const float4*)(fr + c * 4);
        float c0 = 0.f, c1 = 0.f, c2 = 0.f, c3 = 0.f;
        #pragma unroll
        for (int c = 0; c < 8; ++c) {
            float e0 = fdr[c*4+0] + fa[c].x; c0 = fmaf(avs[c*4+0], __builtin_fabsf(e0), c0);
            float e1 = fdr[c*4+1] + fa[c].y; c1 = fmaf(avs[c*4+1], __builtin_fabsf(e1), c1);
            float e2 = fdr[c*4+2] + fa[c].z; c2 = fmaf(avs[c*4+2], __builtin_fabsf(e2), c2);
            float e3 = fdr[c*4+3] + fa[c].w; c3 = fmaf(avs[c*4+3], __builtin_fabsf(e3), c3);
        }
        float v = adc + As06[s] + ((c0 + c1) + (c2 + c3));
        float e = (s == d) ? 0.f : __expf(v);
        Z += e;
        #pragma unroll
        for (int c = 0; c < 8; ++c) {
            acc[c*4+0] = fmaf(e, fa[c].x, acc[c*4+0]);
            acc[c*4+1] = fmaf(e, fa[c].y, acc[c*4+1]);
            acc[c*4+2] = fmaf(e, fa[c].z, acc[c*4+2]);
            acc[c*4+3] = fmaf(e, fa[c].w, acc[c*4+3]);
        }
    }
    Z += __shfl_xor(Z, 1);
    const float rz = fast_rcp(Z);
    #pragma unroll
    for (int o = 0; o < 32; ++o) acc[o] += __shfl_xor(acc[o], 1);

    __syncthreads();
    if ((tid & 1) == 0) {
        #pragma unroll
        for (int c = 0; c < 4; ++c) {
            float4 v;
            v.x = acc[c*4+0] * rz; v.y = acc[c*4+1] * rz;
            v.z = acc[c*4+2] * rz; v.w = acc[c*4+3] * rz;
            *(float4*)&FD[d][c * 4] = v;
        }
    } else {
        #pragma unroll
        for (int c = 4; c < 8; ++c) {
            float4 v;
            v.x = acc[c*4+0] * rz; v.y = acc[c*4+1] * rz;
            v.z = acc[c*4+2] * rz; v.w = acc[c*4+3] * rz;
            *(float4*)&FD[d][c * 4] = v;
        }
    }
    __syncthreads();

    if (tid < 32) {
        float sp = 0.f;
        #pragma unroll 1
        for (int n = 0; n < 128; ++n) sp += FD[n][tid];
        pooled[g * 32 + tid] = fmaf(sp, 1.f / 128.f, b2[tid]);
    }
}

// ---------------------------------------------------------------------------
// Final: cosine sims, contrastive loss, output assembly.
// ---------------------------------------------------------------------------
__global__ void final_kernel(const float* __restrict__ pooled,
                             const float* __restrict__ hideout,
                             const float* __restrict__ timestep,
                             float* __restrict__ out)
{
    const int b = threadIdx.x;
    __shared__ float lossArr[16];
    if (b < 16) {
        const float* A  = pooled + b * 32;
        const float* Pv = pooled + (16 + b) * 32;
        float av[32];
        float na = 0.f;
        #pragma unroll
        for (int i = 0; i < 32; ++i) { av[i] = A[i]; na += av[i] * av[i]; }
        float npv = 0.f, dp = 0.f;
        #pragma unroll
        for (int i = 0; i < 32; ++i) { float p = Pv[i]; npv += p * p; dp += av[i] * p; }
        const float eps = 1e-6f;
        const float ia = 1.f / fmaxf(sqrtf(na), eps);
        const float sp = dp * ia / fmaxf(sqrtf(npv), eps);
        float sn[4];
        #pragma unroll
        for (int k = 0; k < 4; ++k) {
            const float* Nv = pooled + (32 + b * 4 + k) * 32;
            float nn = 0.f, dn = 0.f;
            #pragma unroll
            for (int i = 0; i < 32; ++i) { float q = Nv[i]; nn += q * q; dn += av[i] * q; }
            sn[k] = dn * ia / fmaxf(sqrtf(nn), eps);
        }
        float m = sp;
        #pragma unroll
        for (int k = 0; k < 4; ++k) m = fmaxf(m, sn[k]);
        float Z = expf(sp - m);
        #pragma unroll
        for (int k = 0; k < 4; ++k) Z += expf(sn[k] - m);
        lossArr[b] = logf(Z) + m - sp;
        float* r = out + b * 35;
        #pragma unroll
        for (int i = 0; i < 32; ++i) r[i] = av[i];
        r[32] = hideout[b * 2];
        r[33] = hideout[b * 2 + 1];
        r[34] = timestep[b];
    }
    __syncthreads();
    if (b == 0) {
        float s = 0.f;
        #pragma unroll
        for (int i = 0; i < 16; ++i) s += lossArr[i];
        out[560] = s * (1.f / 16.f);
    }
}

extern "C" void kernel_launch(void* const* d_in, const int* in_sizes, int n_in,
                              void* d_out, int out_size, void* d_ws, size_t ws_size,
                              hipStream_t stream) {
    const float* anchor   = (const float*)d_in[0];
    const float* pos      = (const float*)d_in[1];
    const float* neg      = (const float*)d_in[2];
    const float* hideout  = (const float*)d_in[3];
    const float* timestep = (const float*)d_in[4];
    const float* Wih      = (const float*)d_in[5];
    const float* Whh      = (const float*)d_in[6];
    const float* b_lstm   = (const float*)d_in[7];
    const float* W1s      = (const float*)d_in[8];
    const float* W1d      = (const float*)d_in[9];
    const float* a1       = (const float*)d_in[10];
    const float* b1       = (const float*)d_in[11];
    const float* W2s      = (const float*)d_in[12];
    const float* W2d      = (const float*)d_in[13];
    const float* a2       = (const float*)d_in[14];
    const float* b2       = (const float*)d_in[15];
    float* out = (float*)d_out;

    char* ws = (char*)d_ws;
    float* hn      = (float*)(ws);                       // 12288*32*4   = 1,572,864 B
    float* h1heads = (float*)(ws + 1605632);             // 96*8*128*32*4 = 12,582,912 B
    float* pooled  = (float*)(ws + 14188544);            // 96*32*4      = 12,288 B

    hipLaunchKernelGGL(lstm_mfma_kernel, dim3(96), dim3(256), 0, stream,
                       anchor, pos, neg, Wih, Whh, b_lstm, hn);
    hipLaunchKernelGGL(gat1_kernel,  dim3(768),  dim3(256), 0, stream,
                       hn, W1s, W1d, a1, b1, h1heads);
    hipLaunchKernelGGL(gat2_kernel,  dim3(96),   dim3(256), 0, stream,
                       h1heads, W2s, W2d, a2, b2, pooled);
    hipLaunchKernelGGL(final_kernel, dim3(1),    dim3(64),  0, stream,
                       pooled, hideout, timestep, out);
}

// Round 9
// 166.477 us; speedup vs baseline: 1.4058x; 1.4058x over previous
//
#include <hip/hip_runtime.h>
#include <math.h>

// Problem constants: B=16, K=4, T=64, N=128, F=16, H=32, NH=8, GH=32
// Sequences: 12288 = 2048 anchor + 2048 pos + 8192 neg. Graphs: 96 = 16+16+64.

typedef __bf16 bf16x8 __attribute__((ext_vector_type(8)));
typedef float  f32x4  __attribute__((ext_vector_type(4)));
typedef unsigned int u32x4 __attribute__((ext_vector_type(4)));

__device__ __forceinline__ float fast_rcp(float x) { return __builtin_amdgcn_rcpf(x); }
__device__ __forceinline__ float sigm(float x)     { return fast_rcp(1.f + __expf(-x)); }
__device__ __forceinline__ float tanh_fast(float x){ return fmaf(2.f, fast_rcp(1.f + __expf(-2.f * x)), -1.f); }

#define KEEP4(x) asm volatile("" : "+v"(x))

// ---------------------------------------------------------------------------
// LSTM via MFMA (R7 structure): barrier-free single-wave recurrence, weights
// pinned in VGPRs. Wave owns 16 seqs + all 128 gate cols (8 tiles of 16).
// Per-step h transpose through wave-private LDS (per-wave DS FIFO ordering,
// no __syncthreads). 3 MFMAs/tile: ax*wih_hi + ahi*whh_hi + ahi*whh_lo
// (h_lo term dropped: h bf16-quantization err ~1e-3 -> final ~3e-3 << 4.7e-2).
// h stored as bf16-hi in u32 slots; only hi-perms needed (4 perms/step).
// ---------------------------------------------------------------------------
__global__ __launch_bounds__(256, 1) void lstm_mfma_kernel(
    const float* __restrict__ anchor, const float* __restrict__ pos,
    const float* __restrict__ neg, const float* __restrict__ Wih,
    const float* __restrict__ Whh, const float* __restrict__ bias,
    float* __restrict__ hn)
{
    __shared__ unsigned int Hbuf[4][512];   // wave-private [16 m][32 j]
    const int tid  = threadIdx.x;
    const int w    = tid >> 6;
    const int lane = tid & 63;
    const int l15  = lane & 15;
    const int g4   = lane >> 4;
    unsigned int* hb = Hbuf[w];

    #pragma unroll
    for (int i = 0; i < 8; ++i) hb[lane + i * 64] = 0u;

    // B-fragments (u32x4, asm-pinned) + scalar bias
    u32x4 whhH[8], whhL[8], wihH[8];
    float bq[8];
    #pragma unroll
    for (int f = 0; f < 8; ++f) {
        const int G = f >> 1, Hh = f & 1;
        const int c = G * 32 + Hh * 16 + l15;
        bq[f] = bias[c];
        union { u32x4 u; bf16x8 v; } th, tl, ti;
        const float* wr = Whh + c * 32 + g4 * 8;
        #pragma unroll
        for (int i = 0; i < 8; ++i) {
            float wv = wr[i];
            __bf16 hi = (__bf16)wv;
            th.v[i] = hi;
            tl.v[i] = (__bf16)(wv - (float)hi);
        }
        if (g4 < 2) {
            const float* wr2 = Wih + c * 16 + g4 * 8;
            #pragma unroll
            for (int i = 0; i < 8; ++i) ti.v[i] = (__bf16)wr2[i];
        } else {
            #pragma unroll
            for (int i = 0; i < 8; ++i) ti.v[i] = (__bf16)0.f;
        }
        whhH[f] = th.u; whhL[f] = tl.u; wihH[f] = ti.u;
    }
    #pragma unroll
    for (int f = 0; f < 8; ++f) { KEEP4(whhH[f]); KEEP4(whhL[f]); KEEP4(wihH[f]); }

    // x source: seq s = blk*64 + w*16 + l15, features 8*g4+i (g4<2 only)
    const int s = blockIdx.x * 64 + w * 16 + l15;
    const float* xbase; int sl;
    if (s < 2048)      { xbase = anchor; sl = s; }
    else if (s < 4096) { xbase = pos;    sl = s - 2048; }
    else               { xbase = neg;    sl = s - 4096; }
    const bool xact = (g4 < 2);
    const float* xp = xbase + (sl >> 7) * 131072 + (sl & 127) * 16 + (xact ? g4 * 8 : 0);

    const float4 z4 = make_float4(0.f, 0.f, 0.f, 0.f);
    float4 xaA = z4, xbA = z4, xaB = z4, xbB = z4;
    if (xact) {
        xaA = *(const float4*)(xp);        xbA = *(const float4*)(xp + 4);
        xaB = *(const float4*)(xp + 2048); xbB = *(const float4*)(xp + 2052);
    }

    float cst[8] = {0,0,0,0,0,0,0,0};
    float hv[8]  = {0,0,0,0,0,0,0,0};

    const int c0  = g4 * 2;
    const int swz = (l15 & 3) << 1;
    const int ro0 = l15 * 32 + ((c0 ^ swz) << 2);
    const int ro1 = l15 * 32 + (((c0 + 1) ^ swz) << 2);

    #define LSTM_STEP(XA, XB)                                                          \
    {                                                                                  \
        bf16x8 ax;                                                                     \
        ax[0]=(__bf16)XA.x; ax[1]=(__bf16)XA.y; ax[2]=(__bf16)XA.z; ax[3]=(__bf16)XA.w;\
        ax[4]=(__bf16)XB.x; ax[5]=(__bf16)XB.y; ax[6]=(__bf16)XB.z; ax[7]=(__bf16)XB.w;\
        uint4 v0 = *(const uint4*)(hb + ro0);                                          \
        uint4 v1 = *(const uint4*)(hb + ro1);                                          \
        union { unsigned int u[4]; bf16x8 v; } ahi;                                    \
        ahi.u[0] = __builtin_amdgcn_perm(v0.y, v0.x, 0x05040100u);                     \
        ahi.u[1] = __builtin_amdgcn_perm(v0.w, v0.z, 0x05040100u);                     \
        ahi.u[2] = __builtin_amdgcn_perm(v1.y, v1.x, 0x05040100u);                     \
        ahi.u[3] = __builtin_amdgcn_perm(v1.w, v1.z, 0x05040100u);                     \
        f32x4 z[8];                                                                    \
        _Pragma("unroll")                                                              \
        for (int f = 0; f < 8; ++f) {                                                  \
            f32x4 a = __builtin_amdgcn_mfma_f32_16x16x32_bf16(                         \
                ax, __builtin_bit_cast(bf16x8, wihH[f]), (f32x4)(0.f), 0, 0, 0);       \
            a = __builtin_amdgcn_mfma_f32_16x16x32_bf16(                               \
                ahi.v, __builtin_bit_cast(bf16x8, whhH[f]), a, 0, 0, 0);               \
            a = __builtin_amdgcn_mfma_f32_16x16x32_bf16(                               \
                ahi.v, __builtin_bit_cast(bf16x8, whhL[f]), a, 0, 0, 0);               \
            z[f] = a;                                                                  \
        }                                                                              \
        _Pragma("unroll")                                                              \
        for (int Hh = 0; Hh < 2; ++Hh) {                                               \
            _Pragma("unroll")                                                          \
            for (int r = 0; r < 4; ++r) {                                              \
                const int idx = Hh * 4 + r;                                            \
                float zi = z[0 + Hh][r] + bq[0 + Hh];                                  \
                float zf = z[2 + Hh][r] + bq[2 + Hh];                                  \
                float zg = z[4 + Hh][r] + bq[4 + Hh];                                  \
                float zo = z[6 + Hh][r] + bq[6 + Hh];                                  \
                float cn = fmaf(sigm(zf), cst[idx], sigm(zi) * tanh_fast(zg));         \
                cst[idx] = cn;                                                         \
                float h = sigm(zo) * tanh_fast(cn);                                    \
                hv[idx] = h;                                                           \
                unsigned int pk = (unsigned int)__builtin_bit_cast(unsigned short,     \
                                                                   (__bf16)h);        \
                const int mm = g4 * 4 + r;                                             \
                const int jw = Hh * 16 + l15;                                          \
                hb[mm * 32 + (((jw >> 2) ^ ((mm & 3) << 1)) << 2) + (jw & 3)] = pk;    \
            }                                                                          \
        }                                                                              \
    }

    for (int t = 0; t < 64; t += 2) {
        float4 cA1 = xaA, cA2 = xbA;
        if (xact && t + 2 < 64) {
            const float* p = xp + (t + 2) * 2048;
            xaA = *(const float4*)(p); xbA = *(const float4*)(p + 4);
        }
        LSTM_STEP(cA1, cA2);

        float4 cB1 = xaB, cB2 = xbB;
        if (xact && t + 3 < 64) {
            const float* p = xp + (t + 3) * 2048;
            xaB = *(const float4*)(p); xbB = *(const float4*)(p + 4);
        }
        LSTM_STEP(cB1, cB2);
    }
    #undef LSTM_STEP

    const int seq0 = blockIdx.x * 64 + w * 16;
    #pragma unroll
    for (int Hh = 0; Hh < 2; ++Hh) {
        #pragma unroll
        for (int r = 0; r < 4; ++r) {
            hn[(seq0 + g4 * 4 + r) * 32 + Hh * 16 + l15] = hv[Hh * 4 + r];
        }
    }
}

// FS layout: 4-float shim every 32 rows -> rows {s, s+32, s+64, s+96} land
// 4 banks apart (quarter-split conflict-free); rows {s, s+64} 8 apart.
__device__ __forceinline__ int fsoff(int n) { return n * 36 + ((n >> 5) << 2); }

// ---------------------------------------------------------------------------
// GATv2 layer 1, d-split x2: 1536 blocks = (graph, head, half). Each block
// computes full FS (all 128 source rows) but only its 64 destination rows.
// Fused pass: thread = (d_local = tid>>2, s-quarter of 32); shfl_xor(1,2)
// reduce; sq==0 lane stores. LDS ~28.5 KB -> higher occupancy.
// lrelu split: a.lrelu(e) = 0.6 a.e + 0.4 a.|e|; no-max-shift exp is safe.
// ---------------------------------------------------------------------------
__global__ __launch_bounds__(256) void gat1_kernel(
    const float* __restrict__ hn, const float* __restrict__ W1s,
    const float* __restrict__ W1d, const float* __restrict__ a1,
    const float* __restrict__ b1, float* __restrict__ h1heads)
{
    const int g = blockIdx.x >> 4, hd = (blockIdx.x >> 1) & 7, half = blockIdx.x & 1;
    const int dbase = half << 6;
    __shared__ float FSf[128 * 36 + 16];
    __shared__ float FD[64][36];
    __shared__ float AVr[32];
    __shared__ float As06[128];
    __shared__ float Ad06[64];
    const int tid = threadIdx.x;

    if (tid < 32) AVr[tid] = a1[hd * 32 + tid];

    // Phase A: FS for all 128 rows; FD only for this block's 64 d rows.
    {
        const int o = tid & 31, nb = tid >> 5;       // nb: 16-row slab
        float wcs[32], wcd[32];
        const float* wsp = W1s + hd * 1024 + o;
        const float* wdp = W1d + hd * 1024 + o;
        #pragma unroll
        for (int k = 0; k < 32; ++k) { wcs[k] = wsp[k * 32]; wcd[k] = wdp[k * 32]; }
        const float* hp = hn + g * 4096 + nb * 512;
        const bool own = (nb >> 2) == half;          // slab inside our d-half?
        #pragma unroll 1
        for (int n = 0; n < 16; ++n) {
            const int row = nb * 16 + n;
            float a0 = 0.f, a1_ = 0.f, b0 = 0.f, b1_ = 0.f;
            #pragma unroll
            for (int k0 = 0; k0 < 32; k0 += 4) {
                float4 hv = *(const float4*)(hp + n * 32 + k0);
                a0 = fmaf(hv.x, wcs[k0+0], a0); b0 = fmaf(hv.x, wcd[k0+0], b0);
                a1_ = fmaf(hv.y, wcs[k0+1], a1_); b1_ = fmaf(hv.y, wcd[k0+1], b1_);
                a0 = fmaf(hv.z, wcs[k0+2], a0); b0 = fmaf(hv.z, wcd[k0+2], b0);
                a1_ = fmaf(hv.w, wcs[k0+3], a1_); b1_ = fmaf(hv.w, wcd[k0+3], b1_);
            }
            FSf[fsoff(row) + o] = a0 + a1_;
            if (own) FD[row - dbase][o] = b0 + b1_;
        }
    }
    __syncthreads();

    // As06 for all 128 s; Ad06 for our 64 d.
    if (tid < 128) {
        float ss = 0.f;
        const float* fr = FSf + fsoff(tid);
        #pragma unroll
        for (int oo = 0; oo < 32; ++oo) {
            int o = (oo + tid) & 31;
            ss = fmaf(AVr[o], fr[o], ss);
        }
        As06[tid] = 0.6f * ss;
    } else if (tid < 192) {
        const int dl = tid - 128;
        float sd = 0.f;
        #pragma unroll
        for (int oo = 0; oo < 32; ++oo) {
            int o = (oo + dl) & 31;
            sd = fmaf(AVr[o], FD[dl][o], sd);
        }
        Ad06[dl] = 0.6f * sd;
    }
    __syncthreads();

    const int dl = tid >> 2, d = dbase + dl, sq = tid & 3, sbase = sq << 5;
    float fdr[32], avs[32];
    #pragma unroll
    for (int c = 0; c < 8; ++c) {
        float4 v = *(const float4*)&FD[dl][c * 4];
        fdr[c*4+0] = v.x; fdr[c*4+1] = v.y; fdr[c*4+2] = v.z; fdr[c*4+3] = v.w;
        float4 wv = *(const float4*)&AVr[c * 4];
        avs[c*4+0] = 0.4f * wv.x; avs[c*4+1] = 0.4f * wv.y;
        avs[c*4+2] = 0.4f * wv.z; avs[c*4+3] = 0.4f * wv.w;
    }
    const float adc = Ad06[dl];

    float Z = 0.f;
    float acc[32];
    #pragma unroll
    for (int o = 0; o < 32; ++o) acc[o] = 0.f;
    #pragma unroll 1
    for (int si = 0; si < 32; ++si) {
        const int s = sbase + si;
        const float* fr = FSf + fsoff(s);
        float4 fa[8];
        #pragma unroll
        for (int c = 0; c < 8; ++c) fa[c] = *(const float4*)(fr + c * 4);
        float c0 = 0.f, c1 = 0.f, c2 = 0.f, c3 = 0.f;
        #pragma unroll
        for (int c = 0; c < 8; ++c) {
            float e0 = fdr[c*4+0] + fa[c].x; c0 = fmaf(avs[c*4+0], __builtin_fabsf(e0), c0);
            float e1 = fdr[c*4+1] + fa[c].y; c1 = fmaf(avs[c*4+1], __builtin_fabsf(e1), c1);
            float e2 = fdr[c*4+2] + fa[c].z; c2 = fmaf(avs[c*4+2], __builtin_fabsf(e2), c2);
            float e3 = fdr[c*4+3] + fa[c].w; c3 = fmaf(avs[c*4+3], __builtin_fabsf(e3), c3);
        }
        float v = adc + As06[s] + ((c0 + c1) + (c2 + c3));
        float e = (s == d) ? 0.f : __expf(v);
        Z += e;
        #pragma unroll
        for (int c = 0; c < 8; ++c) {
            acc[c*4+0] = fmaf(e, fa[c].x, acc[c*4+0]);
            acc[c*4+1] = fmaf(e, fa[c].y, acc[c*4+1]);
            acc[c*4+2] = fmaf(e, fa[c].z, acc[c*4+2]);
            acc[c*4+3] = fmaf(e, fa[c].w, acc[c*4+3]);
        }
    }
    Z += __shfl_xor(Z, 1); Z += __shfl_xor(Z, 2);
    const float rz = fast_rcp(Z);
    #pragma unroll
    for (int o = 0; o < 32; ++o) {
        acc[o] += __shfl_xor(acc[o], 1);
        acc[o] += __shfl_xor(acc[o], 2);
    }

    if (sq == 0) {
        float* dst = h1heads + ((size_t)((g * 8 + hd) * 128 + d)) * 32;
        const float* bp = b1 + hd * 32;
        #pragma unroll
        for (int c = 0; c < 8; ++c) {
            float4 v;
            v.x = fmaf(acc[c*4+0], rz, bp[c*4+0]);
            v.y = fmaf(acc[c*4+1], rz, bp[c*4+1]);
            v.z = fmaf(acc[c*4+2], rz, bp[c*4+2]);
            v.w = fmaf(acc[c*4+3], rz, bp[c*4+3]);
            *(float4*)(dst + c * 4) = v;
        }
    }
}

// ---------------------------------------------------------------------------
// GATv2 layer 2, single-pass, staggered FS (s,s+64 -> 8 banks apart):
// one block per graph, 256 threads, (d, s-half) split.
// ---------------------------------------------------------------------------
__global__ __launch_bounds__(256) void gat2_kernel(
    const float* __restrict__ h1heads, const float* __restrict__ W2s,
    const float* __restrict__ W2d, const float* __restrict__ a2,
    const float* __restrict__ b2, float* __restrict__ pooled)
{
    const int g = blockIdx.x;
    __shared__ float HS[128][36];
    __shared__ float FSf[128 * 36 + 16];
    __shared__ float FD[128][36];     // reused as OUT after the fused pass
    __shared__ float AVr[32];
    __shared__ float As06[128];
    __shared__ float Ad06[128];
    const int tid = threadIdx.x;

    if (tid < 32) AVr[tid] = a2[tid];

    {
        #pragma unroll
        for (int i = 0; i < 4; ++i) {
            int idx4 = i * 256 + tid;
            float sx = 0.f, sy = 0.f, sz = 0.f, sw = 0.f;
            #pragma unroll
            for (int hdd = 0; hdd < 8; ++hdd) {
                const float4* src = (const float4*)(h1heads + (size_t)(g * 8 + hdd) * 4096);
                float4 v = src[idx4];
                sx += v.x; sy += v.y; sz += v.z; sw += v.w;
            }
            int n = idx4 >> 3, k0 = (idx4 & 7) * 4;
            float4 r; r.x = sx * 0.125f; r.y = sy * 0.125f; r.z = sz * 0.125f; r.w = sw * 0.125f;
            *(float4*)&HS[n][k0] = r;
        }
    }
    __syncthreads();

    {
        const int o = tid & 31, nb = tid >> 5;
        float wcs[32], wcd[32];
        const float* wsp = W2s + o;
        const float* wdp = W2d + o;
        #pragma unroll
        for (int k = 0; k < 32; ++k) { wcs[k] = wsp[k * 32]; wcd[k] = wdp[k * 32]; }
        #pragma unroll 1
        for (int n = nb * 16; n < nb * 16 + 16; ++n) {
            float a0 = 0.f, a1_ = 0.f, b0 = 0.f, b1_ = 0.f;
            #pragma unroll
            for (int k0 = 0; k0 < 32; k0 += 4) {
                const float4 hv = *(const float4*)&HS[n][k0];
                a0 = fmaf(hv.x, wcs[k0+0], a0); b0 = fmaf(hv.x, wcd[k0+0], b0);
                a1_ = fmaf(hv.y, wcs[k0+1], a1_); b1_ = fmaf(hv.y, wcd[k0+1], b1_);
                a0 = fmaf(hv.z, wcs[k0+2], a0); b0 = fmaf(hv.z, wcd[k0+2], b0);
                a1_ = fmaf(hv.w, wcs[k0+3], a1_); b1_ = fmaf(hv.w, wcd[k0+3], b1_);
            }
            FSf[fsoff(n) + o] = a0 + a1_;
            FD[n][o] = b0 + b1_;
        }
    }
    __syncthreads();

    if (tid < 128) {
        float ss = 0.f, sd = 0.f;
        const float* fr = FSf + fsoff(tid);
        #pragma unroll
        for (int oo = 0; oo < 32; ++oo) {
            int o = (oo + tid) & 31;
            float a = AVr[o];
            ss = fmaf(a, fr[o], ss);
            sd = fmaf(a, FD[tid][o], sd);
        }
        As06[tid] = 0.6f * ss;
        Ad06[tid] = 0.6f * sd;
    }
    __syncthreads();

    const int d = tid >> 1, sbase = (tid & 1) << 6;
    float fdr[32], avs[32];
    #pragma unroll
    for (int c = 0; c < 8; ++c) {
        float4 v = *(const float4*)&FD[d][c * 4];
        fdr[c*4+0] = v.x; fdr[c*4+1] = v.y; fdr[c*4+2] = v.z; fdr[c*4+3] = v.w;
        float4 wv = *(const float4*)&AVr[c * 4];
        avs[c*4+0] = 0.4f * wv.x; avs[c*4+1] = 0.4f * wv.y;
        avs[c*4+2] = 0.4f * wv.z; avs[c*4+3] = 0.4f * wv.w;
    }
    const float adc = Ad06[d];

    float Z = 0.f;
    float acc[32];
    #pragma unroll
    for (int o = 0; o < 32; ++o) acc[o] = 0.f;
    #pragma unroll 1
    for (int si = 0; si < 64; ++si) {
        const int s = sbase + si;
        const float* fr = FSf + fsoff(s);
        float4 fa[8];
        #pragma unroll
        for (int c = 0; c < 8; ++c) fa[c] = *(const float4*)(fr + c * 4);
        float c0 = 0.f, c1 = 0.f, c2 = 0.f, c3 = 0.f;
        #pragma unroll
        for (int c = 0; c < 8; ++c) {
            float e0 = fdr[c*4+0] + fa[c].x; c0 = fmaf(avs[c*4+0], __builtin_fabsf(e0), c0);
            float e1 = fdr[c*4+1] + fa[c].y; c1 = fmaf(avs[c*4+1], __builtin_fabsf(e1), c1);
            float e2 = fdr[c*4+2] + fa[c].z; c2 = fmaf(avs[c*4+2], __builtin_fabsf(e2), c2);
            float e3 = fdr[c*4+3] + fa[c].w; c3 = fmaf(avs[c*4+3], __builtin_fabsf(e3), c3);
        }
        float v = adc + As06[s] + ((c0 + c1) + (c2 + c3));
        float e = (s == d) ? 0.f : __expf(v);
        Z += e;
        #pragma unroll
        for (int c = 0; c < 8; ++c) {
            acc[c*4+0] = fmaf(e, fa[c].x, acc[c*4+0]);
            acc[c*4+1] = fmaf(e, fa[c].y, acc[c*4+1]);
            acc[c*4+2] = fmaf(e, fa[c].z, acc[c*4+2]);
            acc[c*4+3] = fmaf(e, fa[c].w, acc[c*4+3]);
        }
    }
    Z += __shfl_xor(Z, 1);
    const float rz = fast_rcp(Z);
    #pragma unroll
    for (int o = 0; o < 32; ++o) acc[o] += __shfl_xor(acc[o], 1);

    __syncthreads();
    if ((tid & 1) == 0) {
        #pragma unroll
        for (int c = 0; c < 4; ++c) {
            float4 v;
            v.x = acc[c*4+0] * rz; v.y = acc[c*4+1] * rz;
            v.z = acc[c*4+2] * rz; v.w = acc[c*4+3] * rz;
            *(float4*)&FD[d][c * 4] = v;
        }
    } else {
        #pragma unroll
        for (int c = 4; c < 8; ++c) {
            float4 v;
            v.x = acc[c*4+0] * rz; v.y = acc[c*4+1] * rz;
            v.z = acc[c*4+2] * rz; v.w = acc[c*4+3] * rz;
            *(float4*)&FD[d][c * 4] = v;
        }
    }
    __syncthreads();

    if (tid < 32) {
        float sp = 0.f;
        #pragma unroll 1
        for (int n = 0; n < 128; ++n) sp += FD[n][tid];
        pooled[g * 32 + tid] = fmaf(sp, 1.f / 128.f, b2[tid]);
    }
}

// ---------------------------------------------------------------------------
// Final: cosine sims, contrastive loss, output assembly.
// ---------------------------------------------------------------------------
__global__ void final_kernel(const float* __restrict__ pooled,
                             const float* __restrict__ hideout,
                             const float* __restrict__ timestep,
                             float* __restrict__ out)
{
    const int b = threadIdx.x;
    __shared__ float lossArr[16];
    if (b < 16) {
        const float* A  = pooled + b * 32;
        const float* Pv = pooled + (16 + b) * 32;
        float av[32];
        float na = 0.f;
        #pragma unroll
        for (int i = 0; i < 32; ++i) { av[i] = A[i]; na += av[i] * av[i]; }
        float npv = 0.f, dp = 0.f;
        #pragma unroll
        for (int i = 0; i < 32; ++i) { float p = Pv[i]; npv += p * p; dp += av[i] * p; }
        const float eps = 1e-6f;
        const float ia = 1.f / fmaxf(sqrtf(na), eps);
        const float sp = dp * ia / fmaxf(sqrtf(npv), eps);
        float sn[4];
        #pragma unroll
        for (int k = 0; k < 4; ++k) {
            const float* Nv = pooled + (32 + b * 4 + k) * 32;
            float nn = 0.f, dn = 0.f;
            #pragma unroll
            for (int i = 0; i < 32; ++i) { float q = Nv[i]; nn += q * q; dn += av[i] * q; }
            sn[k] = dn * ia / fmaxf(sqrtf(nn), eps);
        }
        float m = sp;
        #pragma unroll
        for (int k = 0; k < 4; ++k) m = fmaxf(m, sn[k]);
        float Z = expf(sp - m);
        #pragma unroll
        for (int k = 0; k < 4; ++k) Z += expf(sn[k] - m);
        lossArr[b] = logf(Z) + m - sp;
        float* r = out + b * 35;
        #pragma unroll
        for (int i = 0; i < 32; ++i) r[i] = av[i];
        r[32] = hideout[b * 2];
        r[33] = hideout[b * 2 + 1];
        r[34] = timestep[b];
    }
    __syncthreads();
    if (b == 0) {
        float s = 0.f;
        #pragma unroll
        for (int i = 0; i < 16; ++i) s += lossArr[i];
        out[560] = s * (1.f / 16.f);
    }
}

extern "C" void kernel_launch(void* const* d_in, const int* in_sizes, int n_in,
                              void* d_out, int out_size, void* d_ws, size_t ws_size,
                              hipStream_t stream) {
    const float* anchor   = (const float*)d_in[0];
    const float* pos      = (const float*)d_in[1];
    const float* neg      = (const float*)d_in[2];
    const float* hideout  = (const float*)d_in[3];
    const float* timestep = (const float*)d_in[4];
    const float* Wih      = (const float*)d_in[5];
    const float* Whh      = (const float*)d_in[6];
    const float* b_lstm   = (const float*)d_in[7];
    const float* W1s      = (const float*)d_in[8];
    const float* W1d      = (const float*)d_in[9];
    const float* a1       = (const float*)d_in[10];
    const float* b1       = (const float*)d_in[11];
    const float* W2s      = (const float*)d_in[12];
    const float* W2d      = (const float*)d_in[13];
    const float* a2       = (const float*)d_in[14];
    const float* b2       = (const float*)d_in[15];
    float* out = (float*)d_out;

    char* ws = (char*)d_ws;
    float* hn      = (float*)(ws);                       // 12288*32*4   = 1,572,864 B
    float* h1heads = (float*)(ws + 1605632);             // 96*8*128*32*4 = 12,582,912 B
    float* pooled  = (float*)(ws + 14188544);            // 96*32*4      = 12,288 B

    hipLaunchKernelGGL(lstm_mfma_kernel, dim3(192), dim3(256), 0, stream,
                       anchor, pos, neg, Wih, Whh, b_lstm, hn);
    hipLaunchKernelGGL(gat1_kernel,  dim3(1536), dim3(256), 0, stream,
                       hn, W1s, W1d, a1, b1, h1heads);
    hipLaunchKernelGGL(gat2_kernel,  dim3(96),   dim3(256), 0, stream,
                       h1heads, W2s, W2d, a2, b2, pooled);
    hipLaunchKernelGGL(final_kernel, dim3(1),    dim3(64),  0, stream,
                       pooled, hideout, timestep, out);
}

// Round 10
// 162.054 us; speedup vs baseline: 1.4441x; 1.0273x over previous
//
#include <hip/hip_runtime.h>
#include <math.h>

// Problem constants: B=16, K=4, T=64, N=128, F=16, H=32, NH=8, GH=32
// Sequences: 12288 = 2048 anchor + 2048 pos + 8192 neg. Graphs: 96 = 16+16+64.

typedef __bf16 bf16x8 __attribute__((ext_vector_type(8)));
typedef float  f32x4  __attribute__((ext_vector_type(4)));
typedef unsigned int u32x4 __attribute__((ext_vector_type(4)));

__device__ __forceinline__ float fast_rcp(float x) { return __builtin_amdgcn_rcpf(x); }
__device__ __forceinline__ float sigm(float x)     { return fast_rcp(1.f + __expf(-x)); }
__device__ __forceinline__ float tanh_fast(float x){ return fmaf(2.f, fast_rcp(1.f + __expf(-2.f * x)), -1.f); }

#define KEEP4(x) asm volatile("" : "+v"(x))

// ---------------------------------------------------------------------------
// LSTM via MFMA, 2-wave co-op: a wave PAIR shares 16 sequences; wave wid owns
// unit-half jw = wid*16+l15 (4 gate-tiles x 3 MFMAs). Activations per lane:
// 4 elements (40 trans-ops, HALF of the 1-wave design) and the two waves'
// trans streams run on different SIMDs concurrently. Weights asm-pinned
// (12 u32x4/wave). h exchanged via pair-shared double-buffered LDS with one
// __syncthreads per step. 1536 waves total (2x the 1-wave design).
// 3 MFMAs/tile: ax*wih_hi + ahi*whh_hi + ahi*whh_lo (h_lo dropped, ~1e-3 err).
// ---------------------------------------------------------------------------
__global__ __launch_bounds__(256, 1) void lstm_mfma_kernel(
    const float* __restrict__ anchor, const float* __restrict__ pos,
    const float* __restrict__ neg, const float* __restrict__ Wih,
    const float* __restrict__ Whh, const float* __restrict__ bias,
    float* __restrict__ hn)
{
    __shared__ unsigned int Hbuf[2][2][512];   // [pair][dbuf][16 m][32 j]
    const int tid  = threadIdx.x;
    const int pair = tid >> 7;
    const int wid  = (tid >> 6) & 1;
    const int lane = tid & 63;
    const int l15  = lane & 15;
    const int g4   = lane >> 4;

    for (int i = tid; i < 2048; i += 256) ((unsigned int*)Hbuf)[i] = 0u;

    // B-fragments for this wave's 4 tiles (gate G, unit-half wid)
    u32x4 whhH[4], whhL[4], wihH[4];
    float bq[4];
    #pragma unroll
    for (int G = 0; G < 4; ++G) {
        const int c = G * 32 + wid * 16 + l15;
        bq[G] = bias[c];
        union { u32x4 u; bf16x8 v; } th, tl, ti;
        const float* wr = Whh + c * 32 + g4 * 8;
        #pragma unroll
        for (int i = 0; i < 8; ++i) {
            float wv = wr[i];
            __bf16 hi = (__bf16)wv;
            th.v[i] = hi;
            tl.v[i] = (__bf16)(wv - (float)hi);
        }
        if (g4 < 2) {
            const float* wr2 = Wih + c * 16 + g4 * 8;
            #pragma unroll
            for (int i = 0; i < 8; ++i) ti.v[i] = (__bf16)wr2[i];
        } else {
            #pragma unroll
            for (int i = 0; i < 8; ++i) ti.v[i] = (__bf16)0.f;
        }
        whhH[G] = th.u; whhL[G] = tl.u; wihH[G] = ti.u;
    }
    #pragma unroll
    for (int G = 0; G < 4; ++G) { KEEP4(whhH[G]); KEEP4(whhL[G]); KEEP4(wihH[G]); }

    // x source: pair's seqs = blk*32 + pair*16 + l15 (both waves load same x)
    const int s = blockIdx.x * 32 + pair * 16 + l15;
    const float* xbase; int sl;
    if (s < 2048)      { xbase = anchor; sl = s; }
    else if (s < 4096) { xbase = pos;    sl = s - 2048; }
    else               { xbase = neg;    sl = s - 4096; }
    const bool xact = (g4 < 2);
    const float* xp = xbase + (sl >> 7) * 131072 + (sl & 127) * 16 + (xact ? g4 * 8 : 0);

    const float4 z4 = make_float4(0.f, 0.f, 0.f, 0.f);
    float4 xaA = z4, xbA = z4, xaB = z4, xbB = z4;
    if (xact) {
        xaA = *(const float4*)(xp);        xbA = *(const float4*)(xp + 4);
        xaB = *(const float4*)(xp + 2048); xbB = *(const float4*)(xp + 2052);
    }

    float cst[4] = {0,0,0,0};
    float hv[4]  = {0,0,0,0};

    const int c0  = g4 * 2;
    const int swz = (l15 & 3) << 1;
    const int ro0 = l15 * 32 + ((c0 ^ swz) << 2);
    const int ro1 = l15 * 32 + (((c0 + 1) ^ swz) << 2);
    const int jw  = wid * 16 + l15;
    unsigned int* buf0 = Hbuf[pair][0];
    unsigned int* buf1 = Hbuf[pair][1];
    int cur = 0;
    __syncthreads();

    #define LSTM_STEP(XA, XB)                                                          \
    {                                                                                  \
        const unsigned int* rb = cur ? buf1 : buf0;                                    \
        unsigned int*       wb = cur ? buf0 : buf1;                                    \
        bf16x8 ax;                                                                     \
        ax[0]=(__bf16)XA.x; ax[1]=(__bf16)XA.y; ax[2]=(__bf16)XA.z; ax[3]=(__bf16)XA.w;\
        ax[4]=(__bf16)XB.x; ax[5]=(__bf16)XB.y; ax[6]=(__bf16)XB.z; ax[7]=(__bf16)XB.w;\
        uint4 v0 = *(const uint4*)(rb + ro0);                                          \
        uint4 v1 = *(const uint4*)(rb + ro1);                                          \
        union { unsigned int u[4]; bf16x8 v; } ahi;                                    \
        ahi.u[0] = __builtin_amdgcn_perm(v0.y, v0.x, 0x05040100u);                     \
        ahi.u[1] = __builtin_amdgcn_perm(v0.w, v0.z, 0x05040100u);                     \
        ahi.u[2] = __builtin_amdgcn_perm(v1.y, v1.x, 0x05040100u);                     \
        ahi.u[3] = __builtin_amdgcn_perm(v1.w, v1.z, 0x05040100u);                     \
        f32x4 z[4];                                                                    \
        _Pragma("unroll")                                                              \
        for (int G = 0; G < 4; ++G) {                                                  \
            f32x4 a = __builtin_amdgcn_mfma_f32_16x16x32_bf16(                         \
                ax, __builtin_bit_cast(bf16x8, wihH[G]), (f32x4)(0.f), 0, 0, 0);       \
            a = __builtin_amdgcn_mfma_f32_16x16x32_bf16(                               \
                ahi.v, __builtin_bit_cast(bf16x8, whhH[G]), a, 0, 0, 0);               \
            a = __builtin_amdgcn_mfma_f32_16x16x32_bf16(                               \
                ahi.v, __builtin_bit_cast(bf16x8, whhL[G]), a, 0, 0, 0);               \
            z[G] = a;                                                                  \
        }                                                                              \
        _Pragma("unroll")                                                              \
        for (int r = 0; r < 4; ++r) {                                                  \
            float zi = z[0][r] + bq[0];                                                \
            float zf = z[1][r] + bq[1];                                                \
            float zg = z[2][r] + bq[2];                                                \
            float zo = z[3][r] + bq[3];                                                \
            float cn = fmaf(sigm(zf), cst[r], sigm(zi) * tanh_fast(zg));               \
            cst[r] = cn;                                                               \
            float h = sigm(zo) * tanh_fast(cn);                                        \
            hv[r] = h;                                                                 \
            unsigned int pk = (unsigned int)__builtin_bit_cast(unsigned short,         \
                                                               (__bf16)h);            \
            const int mm = g4 * 4 + r;                                                 \
            wb[mm * 32 + (((jw >> 2) ^ ((mm & 3) << 1)) << 2) + (jw & 3)] = pk;        \
        }                                                                              \
        __syncthreads();                                                               \
        cur ^= 1;                                                                      \
    }

    for (int t = 0; t < 64; t += 2) {
        float4 cA1 = xaA, cA2 = xbA;
        if (xact && t + 2 < 64) {
            const float* p = xp + (t + 2) * 2048;
            xaA = *(const float4*)(p); xbA = *(const float4*)(p + 4);
        }
        LSTM_STEP(cA1, cA2);

        float4 cB1 = xaB, cB2 = xbB;
        if (xact && t + 3 < 64) {
            const float* p = xp + (t + 3) * 2048;
            xaB = *(const float4*)(p); xbB = *(const float4*)(p + 4);
        }
        LSTM_STEP(cB1, cB2);
    }
    #undef LSTM_STEP

    // epilogue: hn[seq][unit]; wave writes its unit-half for its pair's seqs
    const int seq0 = blockIdx.x * 32 + pair * 16;
    #pragma unroll
    for (int r = 0; r < 4; ++r) {
        hn[(seq0 + g4 * 4 + r) * 32 + jw] = hv[r];
    }
}

// FS layout: 4-float shim every 32 rows -> rows {s, s+32, s+64, s+96} land
// 4 banks apart (quarter-split conflict-free); rows {s, s+64} 8 apart.
__device__ __forceinline__ int fsoff(int n) { return n * 36 + ((n >> 5) << 2); }

// ---------------------------------------------------------------------------
// GATv2 layer 1, d-split x2 with own-guarded Phase A: 1536 blocks =
// (graph, head, half). FS computed for all 128 source rows; the FD fma chain
// (and its wcd loads) run ONLY in the wave-uniform `own` branch -> non-own
// waves do half the Phase A work. Fused pass: (d_local, s-quarter) with
// shfl_xor(1,2) reduce; sq==0 stores.
// ---------------------------------------------------------------------------
__global__ __launch_bounds__(256) void gat1_kernel(
    const float* __restrict__ hn, const float* __restrict__ W1s,
    const float* __restrict__ W1d, const float* __restrict__ a1,
    const float* __restrict__ b1, float* __restrict__ h1heads)
{
    const int g = blockIdx.x >> 4, hd = (blockIdx.x >> 1) & 7, half = blockIdx.x & 1;
    const int dbase = half << 6;
    __shared__ float FSf[128 * 36 + 16];
    __shared__ float FD[64][36];
    __shared__ float AVr[32];
    __shared__ float As06[128];
    __shared__ float Ad06[64];
    const int tid = threadIdx.x;

    if (tid < 32) AVr[tid] = a1[hd * 32 + tid];

    // Phase A: FS for all 128 rows; FD only in the own branch (wave-uniform).
    {
        const int o = tid & 31, nb = tid >> 5;       // nb: 16-row slab
        const bool own = (nb >> 2) == half;
        float wcs[32];
        const float* wsp = W1s + hd * 1024 + o;
        #pragma unroll
        for (int k = 0; k < 32; ++k) wcs[k] = wsp[k * 32];
        const float* hp = hn + g * 4096 + nb * 512;
        if (own) {
            float wcd[32];
            const float* wdp = W1d + hd * 1024 + o;
            #pragma unroll
            for (int k = 0; k < 32; ++k) wcd[k] = wdp[k * 32];
            #pragma unroll 1
            for (int n = 0; n < 16; ++n) {
                const int row = nb * 16 + n;
                float a0 = 0.f, a1_ = 0.f, b0 = 0.f, b1_ = 0.f;
                #pragma unroll
                for (int k0 = 0; k0 < 32; k0 += 4) {
                    float4 hv = *(const float4*)(hp + n * 32 + k0);
                    a0 = fmaf(hv.x, wcs[k0+0], a0); b0 = fmaf(hv.x, wcd[k0+0], b0);
                    a1_ = fmaf(hv.y, wcs[k0+1], a1_); b1_ = fmaf(hv.y, wcd[k0+1], b1_);
                    a0 = fmaf(hv.z, wcs[k0+2], a0); b0 = fmaf(hv.z, wcd[k0+2], b0);
                    a1_ = fmaf(hv.w, wcs[k0+3], a1_); b1_ = fmaf(hv.w, wcd[k0+3], b1_);
                }
                FSf[fsoff(row) + o] = a0 + a1_;
                FD[row - dbase][o] = b0 + b1_;
            }
        } else {
            #pragma unroll 1
            for (int n = 0; n < 16; ++n) {
                const int row = nb * 16 + n;
                float a0 = 0.f, a1_ = 0.f;
                #pragma unroll
                for (int k0 = 0; k0 < 32; k0 += 4) {
                    float4 hv = *(const float4*)(hp + n * 32 + k0);
                    a0 = fmaf(hv.x, wcs[k0+0], a0);
                    a1_ = fmaf(hv.y, wcs[k0+1], a1_);
                    a0 = fmaf(hv.z, wcs[k0+2], a0);
                    a1_ = fmaf(hv.w, wcs[k0+3], a1_);
                }
                FSf[fsoff(row) + o] = a0 + a1_;
            }
        }
    }
    __syncthreads();

    // As06 for all 128 s; Ad06 for our 64 d.
    if (tid < 128) {
        float ss = 0.f;
        const float* fr = FSf + fsoff(tid);
        #pragma unroll
        for (int oo = 0; oo < 32; ++oo) {
            int o = (oo + tid) & 31;
            ss = fmaf(AVr[o], fr[o], ss);
        }
        As06[tid] = 0.6f * ss;
    } else if (tid < 192) {
        const int dl = tid - 128;
        float sd = 0.f;
        #pragma unroll
        for (int oo = 0; oo < 32; ++oo) {
            int o = (oo + dl) & 31;
            sd = fmaf(AVr[o], FD[dl][o], sd);
        }
        Ad06[dl] = 0.6f * sd;
    }
    __syncthreads();

    const int dl = tid >> 2, d = dbase + dl, sq = tid & 3, sbase = sq << 5;
    float fdr[32], avs[32];
    #pragma unroll
    for (int c = 0; c < 8; ++c) {
        float4 v = *(const float4*)&FD[dl][c * 4];
        fdr[c*4+0] = v.x; fdr[c*4+1] = v.y; fdr[c*4+2] = v.z; fdr[c*4+3] = v.w;
        float4 wv = *(const float4*)&AVr[c * 4];
        avs[c*4+0] = 0.4f * wv.x; avs[c*4+1] = 0.4f * wv.y;
        avs[c*4+2] = 0.4f * wv.z; avs[c*4+3] = 0.4f * wv.w;
    }
    const float adc = Ad06[dl];

    float Z = 0.f;
    float acc[32];
    #pragma unroll
    for (int o = 0; o < 32; ++o) acc[o] = 0.f;
    #pragma unroll 1
    for (int si = 0; si < 32; ++si) {
        const int s = sbase + si;
        const float* fr = FSf + fsoff(s);
        float4 fa[8];
        #pragma unroll
        for (int c = 0; c < 8; ++c) fa[c] = *(const float4*)(fr + c * 4);
        float c0 = 0.f, c1 = 0.f, c2 = 0.f, c3 = 0.f;
        #pragma unroll
        for (int c = 0; c < 8; ++c) {
            float e0 = fdr[c*4+0] + fa[c].x; c0 = fmaf(avs[c*4+0], __builtin_fabsf(e0), c0);
            float e1 = fdr[c*4+1] + fa[c].y; c1 = fmaf(avs[c*4+1], __builtin_fabsf(e1), c1);
            float e2 = fdr[c*4+2] + fa[c].z; c2 = fmaf(avs[c*4+2], __builtin_fabsf(e2), c2);
            float e3 = fdr[c*4+3] + fa[c].w; c3 = fmaf(avs[c*4+3], __builtin_fabsf(e3), c3);
        }
        float v = adc + As06[s] + ((c0 + c1) + (c2 + c3));
        float e = (s == d) ? 0.f : __expf(v);
        Z += e;
        #pragma unroll
        for (int c = 0; c < 8; ++c) {
            acc[c*4+0] = fmaf(e, fa[c].x, acc[c*4+0]);
            acc[c*4+1] = fmaf(e, fa[c].y, acc[c*4+1]);
            acc[c*4+2] = fmaf(e, fa[c].z, acc[c*4+2]);
            acc[c*4+3] = fmaf(e, fa[c].w, acc[c*4+3]);
        }
    }
    Z += __shfl_xor(Z, 1); Z += __shfl_xor(Z, 2);
    const float rz = fast_rcp(Z);
    #pragma unroll
    for (int o = 0; o < 32; ++o) {
        acc[o] += __shfl_xor(acc[o], 1);
        acc[o] += __shfl_xor(acc[o], 2);
    }

    if (sq == 0) {
        float* dst = h1heads + ((size_t)((g * 8 + hd) * 128 + d)) * 32;
        const float* bp = b1 + hd * 32;
        #pragma unroll
        for (int c = 0; c < 8; ++c) {
            float4 v;
            v.x = fmaf(acc[c*4+0], rz, bp[c*4+0]);
            v.y = fmaf(acc[c*4+1], rz, bp[c*4+1]);
            v.z = fmaf(acc[c*4+2], rz, bp[c*4+2]);
            v.w = fmaf(acc[c*4+3], rz, bp[c*4+3]);
            *(float4*)(dst + c * 4) = v;
        }
    }
}

// ---------------------------------------------------------------------------
// GATv2 layer 2, single-pass, staggered FS: one block per graph, 256 threads.
// ---------------------------------------------------------------------------
__global__ __launch_bounds__(256) void gat2_kernel(
    const float* __restrict__ h1heads, const float* __restrict__ W2s,
    const float* __restrict__ W2d, const float* __restrict__ a2,
    const float* __restrict__ b2, float* __restrict__ pooled)
{
    const int g = blockIdx.x;
    __shared__ float HS[128][36];
    __shared__ float FSf[128 * 36 + 16];
    __shared__ float FD[128][36];     // reused as OUT after the fused pass
    __shared__ float AVr[32];
    __shared__ float As06[128];
    __shared__ float Ad06[128];
    const int tid = threadIdx.x;

    if (tid < 32) AVr[tid] = a2[tid];

    {
        #pragma unroll
        for (int i = 0; i < 4; ++i) {
            int idx4 = i * 256 + tid;
            float sx = 0.f, sy = 0.f, sz = 0.f, sw = 0.f;
            #pragma unroll
            for (int hdd = 0; hdd < 8; ++hdd) {
                const float4* src = (const float4*)(h1heads + (size_t)(g * 8 + hdd) * 4096);
                float4 v = src[idx4];
                sx += v.x; sy += v.y; sz += v.z; sw += v.w;
            }
            int n = idx4 >> 3, k0 = (idx4 & 7) * 4;
            float4 r; r.x = sx * 0.125f; r.y = sy * 0.125f; r.z = sz * 0.125f; r.w = sw * 0.125f;
            *(float4*)&HS[n][k0] = r;
        }
    }
    __syncthreads();

    {
        const int o = tid & 31, nb = tid >> 5;
        float wcs[32], wcd[32];
        const float* wsp = W2s + o;
        const float* wdp = W2d + o;
        #pragma unroll
        for (int k = 0; k < 32; ++k) { wcs[k] = wsp[k * 32]; wcd[k] = wdp[k * 32]; }
        #pragma unroll 1
        for (int n = nb * 16; n < nb * 16 + 16; ++n) {
            float a0 = 0.f, a1_ = 0.f, b0 = 0.f, b1_ = 0.f;
            #pragma unroll
            for (int k0 = 0; k0 < 32; k0 += 4) {
                const float4 hv = *(const float4*)&HS[n][k0];
                a0 = fmaf(hv.x, wcs[k0+0], a0); b0 = fmaf(hv.x, wcd[k0+0], b0);
                a1_ = fmaf(hv.y, wcs[k0+1], a1_); b1_ = fmaf(hv.y, wcd[k0+1], b1_);
                a0 = fmaf(hv.z, wcs[k0+2], a0); b0 = fmaf(hv.z, wcd[k0+2], b0);
                a1_ = fmaf(hv.w, wcs[k0+3], a1_); b1_ = fmaf(hv.w, wcd[k0+3], b1_);
            }
            FSf[fsoff(n) + o] = a0 + a1_;
            FD[n][o] = b0 + b1_;
        }
    }
    __syncthreads();

    if (tid < 128) {
        float ss = 0.f, sd = 0.f;
        const float* fr = FSf + fsoff(tid);
        #pragma unroll
        for (int oo = 0; oo < 32; ++oo) {
            int o = (oo + tid) & 31;
            float a = AVr[o];
            ss = fmaf(a, fr[o], ss);
            sd = fmaf(a, FD[tid][o], sd);
        }
        As06[tid] = 0.6f * ss;
        Ad06[tid] = 0.6f * sd;
    }
    __syncthreads();

    const int d = tid >> 1, sbase = (tid & 1) << 6;
    float fdr[32], avs[32];
    #pragma unroll
    for (int c = 0; c < 8; ++c) {
        float4 v = *(const float4*)&FD[d][c * 4];
        fdr[c*4+0] = v.x; fdr[c*4+1] = v.y; fdr[c*4+2] = v.z; fdr[c*4+3] = v.w;
        float4 wv = *(const float4*)&AVr[c * 4];
        avs[c*4+0] = 0.4f * wv.x; avs[c*4+1] = 0.4f * wv.y;
        avs[c*4+2] = 0.4f * wv.z; avs[c*4+3] = 0.4f * wv.w;
    }
    const float adc = Ad06[d];

    float Z = 0.f;
    float acc[32];
    #pragma unroll
    for (int o = 0; o < 32; ++o) acc[o] = 0.f;
    #pragma unroll 1
    for (int si = 0; si < 64; ++si) {
        const int s = sbase + si;
        const float* fr = FSf + fsoff(s);
        float4 fa[8];
        #pragma unroll
        for (int c = 0; c < 8; ++c) fa[c] = *(const float4*)(fr + c * 4);
        float c0 = 0.f, c1 = 0.f, c2 = 0.f, c3 = 0.f;
        #pragma unroll
        for (int c = 0; c < 8; ++c) {
            float e0 = fdr[c*4+0] + fa[c].x; c0 = fmaf(avs[c*4+0], __builtin_fabsf(e0), c0);
            float e1 = fdr[c*4+1] + fa[c].y; c1 = fmaf(avs[c*4+1], __builtin_fabsf(e1), c1);
            float e2 = fdr[c*4+2] + fa[c].z; c2 = fmaf(avs[c*4+2], __builtin_fabsf(e2), c2);
            float e3 = fdr[c*4+3] + fa[c].w; c3 = fmaf(avs[c*4+3], __builtin_fabsf(e3), c3);
        }
        float v = adc + As06[s] + ((c0 + c1) + (c2 + c3));
        float e = (s == d) ? 0.f : __expf(v);
        Z += e;
        #pragma unroll
        for (int c = 0; c < 8; ++c) {
            acc[c*4+0] = fmaf(e, fa[c].x, acc[c*4+0]);
            acc[c*4+1] = fmaf(e, fa[c].y, acc[c*4+1]);
            acc[c*4+2] = fmaf(e, fa[c].z, acc[c*4+2]);
            acc[c*4+3] = fmaf(e, fa[c].w, acc[c*4+3]);
        }
    }
    Z += __shfl_xor(Z, 1);
    const float rz = fast_rcp(Z);
    #pragma unroll
    for (int o = 0; o < 32; ++o) acc[o] += __shfl_xor(acc[o], 1);

    __syncthreads();
    if ((tid & 1) == 0) {
        #pragma unroll
        for (int c = 0; c < 4; ++c) {
            float4 v;
            v.x = acc[c*4+0] * rz; v.y = acc[c*4+1] * rz;
            v.z = acc[c*4+2] * rz; v.w = acc[c*4+3] * rz;
            *(float4*)&FD[d][c * 4] = v;
        }
    } else {
        #pragma unroll
        for (int c = 4; c < 8; ++c) {
            float4 v;
            v.x = acc[c*4+0] * rz; v.y = acc[c*4+1] * rz;
            v.z = acc[c*4+2] * rz; v.w = acc[c*4+3] * rz;
            *(float4*)&FD[d][c * 4] = v;
        }
    }
    __syncthreads();

    if (tid < 32) {
        float sp = 0.f;
        #pragma unroll 1
        for (int n = 0; n < 128; ++n) sp += FD[n][tid];
        pooled[g * 32 + tid] = fmaf(sp, 1.f / 128.f, b2[tid]);
    }
}

// ---------------------------------------------------------------------------
// Final: cosine sims, contrastive loss, output assembly.
// ---------------------------------------------------------------------------
__global__ void final_kernel(const float* __restrict__ pooled,
                             const float* __restrict__ hideout,
                             const float* __restrict__ timestep,
                             float* __restrict__ out)
{
    const int b = threadIdx.x;
    __shared__ float lossArr[16];
    if (b < 16) {
        const float* A  = pooled + b * 32;
        const float* Pv = pooled + (16 + b) * 32;
        float av[32];
        float na = 0.f;
        #pragma unroll
        for (int i = 0; i < 32; ++i) { av[i] = A[i]; na += av[i] * av[i]; }
        float npv = 0.f, dp = 0.f;
        #pragma unroll
        for (int i = 0; i < 32; ++i) { float p = Pv[i]; npv += p * p; dp += av[i] * p; }
        const float eps = 1e-6f;
        const float ia = 1.f / fmaxf(sqrtf(na), eps);
        const float sp = dp * ia / fmaxf(sqrtf(npv), eps);
        float sn[4];
        #pragma unroll
        for (int k = 0; k < 4; ++k) {
            const float* Nv = pooled + (32 + b * 4 + k) * 32;
            float nn = 0.f, dn = 0.f;
            #pragma unroll
            for (int i = 0; i < 32; ++i) { float q = Nv[i]; nn += q * q; dn += av[i] * q; }
            sn[k] = dn * ia / fmaxf(sqrtf(nn), eps);
        }
        float m = sp;
        #pragma unroll
        for (int k = 0; k < 4; ++k) m = fmaxf(m, sn[k]);
        float Z = expf(sp - m);
        #pragma unroll
        for (int k = 0; k < 4; ++k) Z += expf(sn[k] - m);
        lossArr[b] = logf(Z) + m - sp;
        float* r = out + b * 35;
        #pragma unroll
        for (int i = 0; i < 32; ++i) r[i] = av[i];
        r[32] = hideout[b * 2];
        r[33] = hideout[b * 2 + 1];
        r[34] = timestep[b];
    }
    __syncthreads();
    if (b == 0) {
        float s = 0.f;
        #pragma unroll
        for (int i = 0; i < 16; ++i) s += lossArr[i];
        out[560] = s * (1.f / 16.f);
    }
}

extern "C" void kernel_launch(void* const* d_in, const int* in_sizes, int n_in,
                              void* d_out, int out_size, void* d_ws, size_t ws_size,
                              hipStream_t stream) {
    const float* anchor   = (const float*)d_in[0];
    const float* pos      = (const float*)d_in[1];
    const float* neg      = (const float*)d_in[2];
    const float* hideout  = (const float*)d_in[3];
    const float* timestep = (const float*)d_in[4];
    const float* Wih      = (const float*)d_in[5];
    const float* Whh      = (const float*)d_in[6];
    const float* b_lstm   = (const float*)d_in[7];
    const float* W1s      = (const float*)d_in[8];
    const float* W1d      = (const float*)d_in[9];
    const float* a1       = (const float*)d_in[10];
    const float* b1       = (const float*)d_in[11];
    const float* W2s      = (const float*)d_in[12];
    const float* W2d      = (const float*)d_in[13];
    const float* a2       = (const float*)d_in[14];
    const float* b2       = (const float*)d_in[15];
    float* out = (float*)d_out;

    char* ws = (char*)d_ws;
    float* hn      = (float*)(ws);                       // 12288*32*4   = 1,572,864 B
    float* h1heads = (float*)(ws + 1605632);             // 96*8*128*32*4 = 12,582,912 B
    float* pooled  = (float*)(ws + 14188544);            // 96*32*4      = 12,288 B

    hipLaunchKernelGGL(lstm_mfma_kernel, dim3(384), dim3(256), 0, stream,
                       anchor, pos, neg, Wih, Whh, b_lstm, hn);
    hipLaunchKernelGGL(gat1_kernel,  dim3(1536), dim3(256), 0, stream,
                       hn, W1s, W1d, a1, b1, h1heads);
    hipLaunchKernelGGL(gat2_kernel,  dim3(96),   dim3(256), 0, stream,
                       h1heads, W2s, W2d, a2, b2, pooled);
    hipLaunchKernelGGL(final_kernel, dim3(1),    dim3(64),  0, stream,
                       pooled, hideout, timestep, out);
}